// Round 9
// baseline (8895.370 us; speedup 1.0000x reference)
//
#include <hip/hip_runtime.h>
#include <stdint.h>

// LSTM forward T=512, B=64, H=800 — persistent cooperative kernel.
// Round 8 (resubmit): h exchange via REGULAR loads/stores + one __threadfence
// per block per step (wbl2+inv), replacing the agent-scope atomic path whose
// per-op coherence-point cost dominated R6/R7. Same-XCD blocks now share
// h L2 refills (h reads: 20.5 MB/step of atomics -> ~800 KB/step from L3).
// Flag-array barrier + xphase(t+1) overlap retained from R7.
// bf16x3 split-precision MFMA (acc += Ahi*Bhi + Ahi*Blo + Alo*Bhi).
//
// ws layout (bytes):
//   [0,       204800)  c state        (64*800 f32)
//   [204800,  409600)  h_hi[2]        (2 x 64*800 bf16) double-buffered
//   [409600,  614400)  h_lo[2]
//   [614400,  615424)  flags          (200 u32 + pad)
//   [615424,  628224)  biasbuf        (100*32 f32)
//   [628224, 21108224) wbuf           100u x 50kt x {hi,lo} 32x32 bf16 tiles
//   [21108224, 73537024)  xhi  (512*64*800 bf16)  } only if ws_size allows
//   [73537024, 125965824) xlo                     }

#define T_STEPS 512
#define B_SZ    64
#define H_SZ    800
#define KT_X    25
#define KT_TOT  50
#define NU      100
#define NBLK    200

#define OFF_C     0
#define OFF_HHI   204800
#define OFF_HLO   409600
#define OFF_FLAGS 614400
#define OFF_BIAS  615424
#define OFF_WBUF  628224
#define OFF_XHI   21108224ULL
#define OFF_XLO   73537024ULL
#define WS_NEED_PRE 125965824ULL

typedef short bf16x8 __attribute__((ext_vector_type(8)));
typedef float f32x4  __attribute__((ext_vector_type(4)));

__device__ __forceinline__ unsigned short f2bf_rne(float f) {
    unsigned int u = __float_as_uint(f);
    unsigned int r = u + 0x7FFFu + ((u >> 16) & 1u);
    return (unsigned short)(r >> 16);
}
__device__ __forceinline__ float bf2f(unsigned short h) {
    return __uint_as_float(((unsigned int)h) << 16);
}
__device__ __forceinline__ float sigmoid_fast(float v) {
    return 1.f / (1.f + __expf(-v));
}
__device__ __forceinline__ float tanh_fast(float v) {
    v = fminf(fmaxf(v, -15.f), 15.f);
    float e = __expf(2.f * v);
    return (e - 1.f) / (e + 1.f);
}
// trunc-split: hi = trunc-bf16(f), lo = trunc-bf16(f - hi). ~17-bit total.
__device__ __forceinline__ void split2(float f, unsigned short& hi, unsigned short& lo) {
    unsigned int ub = __float_as_uint(f);
    hi = (unsigned short)(ub >> 16);
    float lof = f - __uint_as_float(ub & 0xffff0000u);
    lo = (unsigned short)(__float_as_uint(lof) >> 16);
}

// ---------------------------------------------------------------------------
// One-time prep: W_ih/W_hh -> per-(u,kt) 32x32 bf16 hi/lo MFMA fragment tiles.
// ---------------------------------------------------------------------------
__global__ __launch_bounds__(256) void lstm_prep(
        const float* __restrict__ Wih, const float* __restrict__ Whh,
        const float* __restrict__ bih, const float* __restrict__ bhh,
        unsigned short* __restrict__ wbuf, float* __restrict__ biasbuf) {
    int bid = blockIdx.x;
    int u = bid / KT_TOT, kt = bid % KT_TOT;
    int tid = threadIdx.x;
    int vrow = tid >> 3;
    int kk0  = (tid & 7) * 4;
    int g = vrow >> 3, jj = vrow & 7;
    size_t srow = (size_t)g * H_SZ + u * 8 + jj;
    const float* src = (kt < KT_X)
        ? (Wih + srow * H_SZ + kt * 32 + kk0)
        : (Whh + srow * H_SZ + (kt - KT_X) * 32 + kk0);
    float4 v = *(const float4*)src;
    float f[4] = {v.x, v.y, v.z, v.w};
    unsigned short hi[4], lo[4];
#pragma unroll
    for (int i = 0; i < 4; ++i) {
        hi[i] = f2bf_rne(f[i]);
        lo[i] = f2bf_rne(f[i] - bf2f(hi[i]));
    }
    size_t tbase = ((size_t)u * KT_TOT + kt) * 2048;
    unsigned short* dhi = wbuf + tbase + vrow * 32 + kk0;
    unsigned short* dlo = dhi + 1024;
    *(ushort4*)dhi = make_ushort4(hi[0], hi[1], hi[2], hi[3]);
    *(ushort4*)dlo = make_ushort4(lo[0], lo[1], lo[2], lo[3]);

    if (kt == 0 && tid < 32) {
        int vv = tid;
        size_t r = (size_t)(vv >> 3) * H_SZ + u * 8 + (vv & 7);
        biasbuf[u * 32 + vv] = bih[r] + bhh[r];
    }
}

// ---------------------------------------------------------------------------
// One-time x split: x f32 -> xhi/xlo bf16. 6,553,600 float4s exactly.
// ---------------------------------------------------------------------------
__global__ __launch_bounds__(256) void lstm_xsplit(
        const float* __restrict__ x, unsigned short* __restrict__ xhi,
        unsigned short* __restrict__ xlo) {
    size_t i = (size_t)blockIdx.x * 256 + threadIdx.x;
    float4 v = ((const float4*)x)[i];
    ushort4 h, l;
    split2(v.x, h.x, l.x); split2(v.y, h.y, l.y);
    split2(v.z, h.z, l.z); split2(v.w, h.w, l.w);
    ((ushort4*)xhi)[i] = h;
    ((ushort4*)xlo)[i] = l;
}

// ---------------------------------------------------------------------------
// Phase helpers: batched load -> dual-chain MFMA. NKT is compile-time.
// ---------------------------------------------------------------------------
template<int NKT>
__device__ __forceinline__ f32x4 xphase_pre(const unsigned short* xh,
                                            const unsigned short* xl,
                                            const unsigned short* wt) {
    bf16x8 ah[NKT], al[NKT], bh[NKT], bl[NKT];
#pragma unroll
    for (int i = 0; i < NKT; ++i) {
        ah[i] = *(const bf16x8*)(xh + i * 32);
        al[i] = *(const bf16x8*)(xl + i * 32);
    }
#pragma unroll
    for (int i = 0; i < NKT; ++i) {
        bh[i] = *(const bf16x8*)(wt + (size_t)i * 2048);
        bl[i] = *(const bf16x8*)(wt + (size_t)i * 2048 + 1024);
    }
    f32x4 a0 = {0.f, 0.f, 0.f, 0.f}, a1 = {0.f, 0.f, 0.f, 0.f};
#pragma unroll
    for (int i = 0; i < NKT; ++i) {
        f32x4& a = (i & 1) ? a1 : a0;
        a = __builtin_amdgcn_mfma_f32_16x16x32_bf16(ah[i], bh[i], a, 0, 0, 0);
        a = __builtin_amdgcn_mfma_f32_16x16x32_bf16(ah[i], bl[i], a, 0, 0, 0);
        a = __builtin_amdgcn_mfma_f32_16x16x32_bf16(al[i], bh[i], a, 0, 0, 0);
    }
    return a0 + a1;
}

template<int NKT>
__device__ __forceinline__ f32x4 xphase_cvt(const float* xp,
                                            const unsigned short* wt) {
    float4 xr[2 * NKT];
#pragma unroll
    for (int i = 0; i < NKT; ++i) {
        xr[2 * i]     = *(const float4*)(xp + i * 32);
        xr[2 * i + 1] = *(const float4*)(xp + i * 32 + 4);
    }
    bf16x8 bh[NKT], bl[NKT];
#pragma unroll
    for (int i = 0; i < NKT; ++i) {
        bh[i] = *(const bf16x8*)(wt + (size_t)i * 2048);
        bl[i] = *(const bf16x8*)(wt + (size_t)i * 2048 + 1024);
    }
    f32x4 a0 = {0.f, 0.f, 0.f, 0.f}, a1 = {0.f, 0.f, 0.f, 0.f};
#pragma unroll
    for (int i = 0; i < NKT; ++i) {
        float f[8] = {xr[2*i].x, xr[2*i].y, xr[2*i].z, xr[2*i].w,
                      xr[2*i+1].x, xr[2*i+1].y, xr[2*i+1].z, xr[2*i+1].w};
        bf16x8 ah, al;
#pragma unroll
        for (int j = 0; j < 8; ++j) {
            unsigned short h16, l16;
            split2(f[j], h16, l16);
            ah[j] = (short)h16; al[j] = (short)l16;
        }
        f32x4& a = (i & 1) ? a1 : a0;
        a = __builtin_amdgcn_mfma_f32_16x16x32_bf16(ah, bh[i], a, 0, 0, 0);
        a = __builtin_amdgcn_mfma_f32_16x16x32_bf16(ah, bl[i], a, 0, 0, 0);
        a = __builtin_amdgcn_mfma_f32_16x16x32_bf16(al, bh[i], a, 0, 0, 0);
    }
    return a0 + a1;
}

template<int NKT>
__device__ __forceinline__ f32x4 hphase(const unsigned short* hh,
                                        const unsigned short* hl,
                                        const unsigned short* wlds, f32x4 acc) {
    bf16x8 ah[NKT], al[NKT], bh[NKT], bl[NKT];
#pragma unroll
    for (int i = 0; i < NKT; ++i) {
        ah[i] = *(const bf16x8*)(hh + i * 32);   // regular loads: L1/L2 path,
        al[i] = *(const bf16x8*)(hl + i * 32);   // coherence via per-step fence
    }
#pragma unroll
    for (int i = 0; i < NKT; ++i) {
        bh[i] = *(const bf16x8*)(wlds + (size_t)i * 2048);
        bl[i] = *(const bf16x8*)(wlds + (size_t)i * 2048 + 1024);
    }
    f32x4 a0 = acc, a1 = {0.f, 0.f, 0.f, 0.f};
#pragma unroll
    for (int i = 0; i < NKT; ++i) {
        f32x4& a = (i & 1) ? a1 : a0;
        a = __builtin_amdgcn_mfma_f32_16x16x32_bf16(ah[i], bh[i], a, 0, 0, 0);
        a = __builtin_amdgcn_mfma_f32_16x16x32_bf16(ah[i], bl[i], a, 0, 0, 0);
        a = __builtin_amdgcn_mfma_f32_16x16x32_bf16(al[i], bh[i], a, 0, 0, 0);
    }
    return a0 + a1;
}

// ---------------------------------------------------------------------------
// Persistent kernel: 200 blocks (u, mhalf) x 512 threads (8 waves).
// Wave w: nt=w&1, mt=(w>>1)&1, kh=w>>2 (K halves 13/12 kt).
// Per step: hphase -> epilogue -> sync -> tid0{fence; flag} -> xphase(t+1)
//           [overlapped with others' arrivals] -> parallel poll -> sync.
// Coherence: h stores drain to L2 at the sync; tid0's __threadfence
// writes back dirty L2 (h -> L3) and invalidates L1/L2 BEFORE the flag
// store, so (a) a consumer observing flag=t+1 finds h_t at the coherence
// point, (b) any h-parity line entering this XCD's L2 after the fence
// comes from a post-publication read (all h-phases are barrier-separated),
// hence fresh. No dependence on block->XCD placement.
// ---------------------------------------------------------------------------
__global__ __launch_bounds__(512, 2) void lstm_persist(
        const float* __restrict__ x,
        const unsigned short* __restrict__ wbuf,
        const float* __restrict__ biasbuf,
        unsigned short* __restrict__ hhi,   // [2][64][800]
        unsigned short* __restrict__ hlo,
        float* __restrict__ cbuf,
        float* __restrict__ out,
        unsigned int* __restrict__ flags,   // [NBLK]
        const unsigned short* __restrict__ xhi,
        const unsigned short* __restrict__ xlo,
        int use_pre) {
    extern __shared__ unsigned short whh[];   // 25 kt * 2048 shorts = 102400 B
    __shared__ float gl[2][32][33];

    int bid = blockIdx.x;
    int u = bid >> 1, mhalf = bid & 1;
    int tid = threadIdx.x;
    int lane = tid & 63;
    int w = tid >> 6;
    int nt = w & 1, mt = (w >> 1) & 1, kh = w >> 2;
    int rlane = lane & 15, ksel = lane >> 4, kgrp = ksel * 8;
    int brow = mhalf * 32 + mt * 16 + rlane;

    // ---- stage this u's W_hh tiles (kt 25..49) into LDS ----
    {
        const uint4* src = (const uint4*)(wbuf + ((size_t)u * KT_TOT + KT_X) * 2048);
        uint4* dst = (uint4*)whh;
        for (int g = tid; g < 6400; g += 512) dst[g] = src[g];
    }
    __syncthreads();

    const unsigned short* wih_tile =
        wbuf + (size_t)u * KT_TOT * 2048 + (nt * 16 + rlane) * 32 + kgrp;
    const unsigned short* whh_tile = whh + (nt * 16 + rlane) * 32 + kgrp;

    // epilogue constants (tid<256 -> 32 batch-rows x 8 units)
    int bl_ = tid >> 3, jl = tid & 7;
    int b  = mhalf * 32 + bl_;
    int ju = u * 8 + jl;
    size_t sidx = (size_t)b * H_SZ + ju;
    float b_i = 0.f, b_f = 0.f, b_g = 0.f, b_o = 0.f;
    if (tid < 256) {
        b_i = biasbuf[u * 32 + jl];
        b_f = biasbuf[u * 32 + 8 + jl];
        b_g = biasbuf[u * 32 + 16 + jl];
        b_o = biasbuf[u * 32 + 24 + jl];
    }

    // x contribution for a given timestep (wave's K-half)
    auto do_xphase = [&](int tt) -> f32x4 {
        if (use_pre) {
            const unsigned short* xh = xhi + ((size_t)tt * B_SZ + brow) * H_SZ + kgrp;
            const unsigned short* xl = xlo + ((size_t)tt * B_SZ + brow) * H_SZ + kgrp;
            return (kh == 0) ? xphase_pre<13>(xh, xl, wih_tile)
                             : xphase_pre<12>(xh + 13 * 32, xl + 13 * 32,
                                              wih_tile + 13 * 2048);
        } else {
            const float* xrow = x + ((size_t)tt * B_SZ + brow) * H_SZ + kgrp;
            return (kh == 0) ? xphase_cvt<13>(xrow, wih_tile)
                             : xphase_cvt<12>(xrow + 13 * 32, wih_tile + 13 * 2048);
        }
    };

    f32x4 xacc = do_xphase(0);

    for (int t = 0; t < T_STEPS; ++t) {
        // ---- h phase: A = h_{t-1} regular loads, B from LDS ----
        {
            int pprev = (t + 1) & 1;
            const unsigned short* hh =
                hhi + (size_t)pprev * 51200 + (size_t)brow * H_SZ + kgrp;
            const unsigned short* hl =
                hlo + (size_t)pprev * 51200 + (size_t)brow * H_SZ + kgrp;
            xacc = (kh == 0)
                ? hphase<13>(hh, hl, whh_tile, xacc)
                : hphase<12>(hh + 13 * 32, hl + 13 * 32,
                             whh_tile + 13 * 2048, xacc);
        }

        // ---- gate exchange + epilogue ----
#pragma unroll
        for (int j = 0; j < 4; ++j)
            gl[kh][mt * 16 + ksel * 4 + j][nt * 16 + rlane] = xacc[j];
        __syncthreads();
        if (tid < 256) {
            float gi = gl[0][bl_][jl]      + gl[1][bl_][jl]      + b_i;
            float gf = gl[0][bl_][8 + jl]  + gl[1][bl_][8 + jl]  + b_f;
            float gg = gl[0][bl_][16 + jl] + gl[1][bl_][16 + jl] + b_g;
            float go = gl[0][bl_][24 + jl] + gl[1][bl_][24 + jl] + b_o;
            float cold = cbuf[sidx];
            float ig = sigmoid_fast(gi);
            float fg = sigmoid_fast(gf);
            float gt = tanh_fast(gg);
            float og = sigmoid_fast(go);
            float cn = fg * cold + ig * gt;
            float hn = og * tanh_fast(cn);
            cbuf[sidx] = cn;
            __builtin_nontemporal_store(hn, out + ((size_t)t * B_SZ + b) * H_SZ + ju);
            unsigned short h16, l16;
            split2(hn, h16, l16);
            size_t pcur = (size_t)(t & 1) * 51200;
            hhi[pcur + sidx] = h16;               // regular stores; published
            hlo[pcur + sidx] = l16;               // by the fence below
        }

        // ---- drain h stores to L2 (syncthreads = vmcnt(0) for every wave),
        //      then tid0: fence (wbl2 h->L3 + inv stale L1/L2), arrive ----
        __syncthreads();
        if (tid == 0) {
            __threadfence();
            __hip_atomic_store(flags + bid, (unsigned)(t + 1),
                               __ATOMIC_RELAXED, __HIP_MEMORY_SCOPE_AGENT);
        }

        // ---- overlap: next step's x contribution while others arrive ----
        if (t + 1 < T_STEPS)
            xacc = do_xphase(t + 1);

        // ---- parallel poll: 200 threads each watch one flag ----
        if (tid < NBLK) {
            while (__hip_atomic_load(flags + tid, __ATOMIC_RELAXED,
                                     __HIP_MEMORY_SCOPE_AGENT) < (unsigned)(t + 1))
                __builtin_amdgcn_s_sleep(1);
        }
        __syncthreads();
    }
}

// ---------------------------------------------------------------------------
extern "C" void kernel_launch(void* const* d_in, const int* in_sizes, int n_in,
                              void* d_out, int out_size, void* d_ws, size_t ws_size,
                              hipStream_t stream) {
    const float* x   = (const float*)d_in[0];
    const float* Wih = (const float*)d_in[1];
    const float* Whh = (const float*)d_in[2];
    const float* bih = (const float*)d_in[3];
    const float* bhh = (const float*)d_in[4];
    float* out = (float*)d_out;

    char* ws = (char*)d_ws;
    float* cbuf          = (float*)(ws + OFF_C);
    unsigned short* hhi  = (unsigned short*)(ws + OFF_HHI);
    unsigned short* hlo  = (unsigned short*)(ws + OFF_HLO);
    unsigned int* flags  = (unsigned int*)(ws + OFF_FLAGS);
    float* biasbuf       = (float*)(ws + OFF_BIAS);
    unsigned short* wbuf = (unsigned short*)(ws + OFF_WBUF);
    unsigned short* xhi  = (unsigned short*)(ws + OFF_XHI);
    unsigned short* xlo  = (unsigned short*)(ws + OFF_XLO);
    int use_pre = (ws_size >= WS_NEED_PRE) ? 1 : 0;

    // zero c, h[2] (hi/lo), flags (ws is re-poisoned before each call)
    hipMemsetAsync(ws, 0, OFF_BIAS, stream);

    lstm_prep<<<NU * KT_TOT, 256, 0, stream>>>(Wih, Whh, bih, bhh, wbuf, biasbuf);
    if (use_pre)
        lstm_xsplit<<<25600, 256, 0, stream>>>(x, xhi, xlo);

    hipFuncSetAttribute((const void*)lstm_persist,
                        hipFuncAttributeMaxDynamicSharedMemorySize, 102400);
    void* args[] = {(void*)&x, (void*)&wbuf, (void*)&biasbuf, (void*)&hhi,
                    (void*)&hlo, (void*)&cbuf, (void*)&out, (void*)&flags,
                    (void*)&xhi, (void*)&xlo, (void*)&use_pre};
    hipLaunchCooperativeKernel((const void*)lstm_persist, dim3(NBLK), dim3(512),
                               args, 102400, stream);
}

// Round 13
// 4639.180 us; speedup vs baseline: 1.9174x; 1.9174x over previous
//
#include <hip/hip_runtime.h>
#include <stdint.h>

// LSTM forward T=512, B=64, H=800 — persistent cooperative kernel.
// Round 10 design (compile-fixed): R7's all-sc1 h exchange (best so far,
// 7160us), attacking sc1 op throughput: nt-merged waves (h read once, not
// twice), dwordx4 sc1 loads (half the ops), hierarchical barrier (100x less
// poll traffic), paired 4B h stores. bf16x3 split MFMA unchanged.
// Fix vs R12: __builtin_nontemporal_store needs a native ext_vector type,
// not HIP's struct float2.
//
// ws layout (bytes):
//   [0,       204800)  c state        (64*800 f32)
//   [204800,  409600)  h_hi[2]        (2 x 64*800 bf16) double-buffered
//   [409600,  614400)  h_lo[2]
//   [614400,  615424)  flags[200] + gen word (flags[208])
//   [615424,  628224)  biasbuf        (100*32 f32)
//   [628224, 21108224) wbuf           100u x 50kt x {hi,lo} 32x32 bf16 tiles
//   [21108224, 73537024)  xhi  (512*64*800 bf16)  } only if ws_size allows
//   [73537024, 125965824) xlo                     }

#define T_STEPS 512
#define B_SZ    64
#define H_SZ    800
#define KT_X    25
#define KT_TOT  50
#define NU      100
#define NBLK    200

#define OFF_C     0
#define OFF_HHI   204800
#define OFF_HLO   409600
#define OFF_FLAGS 614400
#define OFF_BIAS  615424
#define OFF_WBUF  628224
#define OFF_XHI   21108224ULL
#define OFF_XLO   73537024ULL
#define WS_NEED_PRE 125965824ULL

typedef short bf16x8 __attribute__((ext_vector_type(8)));
typedef float f32x4  __attribute__((ext_vector_type(4)));
typedef float f32x2  __attribute__((ext_vector_type(2)));
typedef int   i32x4  __attribute__((ext_vector_type(4)));

union CvtAB { i32x4 i; bf16x8 b; };

__device__ __forceinline__ unsigned short f2bf_rne(float f) {
    unsigned int u = __float_as_uint(f);
    unsigned int r = u + 0x7FFFu + ((u >> 16) & 1u);
    return (unsigned short)(r >> 16);
}
__device__ __forceinline__ float bf2f(unsigned short h) {
    return __uint_as_float(((unsigned int)h) << 16);
}
__device__ __forceinline__ float sigmoid_fast(float v) {
    return 1.f / (1.f + __expf(-v));
}
__device__ __forceinline__ float tanh_fast(float v) {
    v = fminf(fmaxf(v, -15.f), 15.f);
    float e = __expf(2.f * v);
    return (e - 1.f) / (e + 1.f);
}
__device__ __forceinline__ void split2(float f, unsigned short& hi, unsigned short& lo) {
    unsigned int ub = __float_as_uint(f);
    hi = (unsigned short)(ub >> 16);
    float lof = f - __uint_as_float(ub & 0xffff0000u);
    lo = (unsigned short)(__float_as_uint(lof) >> 16);
}
// 16B coherence-point load (bypasses L1/L2) — same semantics as the proven
// 8B agent-scope atomic loads, half the op count.
__device__ __forceinline__ i32x4 ld16_sc1(const unsigned short* p) {
    i32x4 r;
    asm volatile("global_load_dwordx4 %0, %1, off sc1"
                 : "=&v"(r) : "v"(p) : "memory");
    return r;
}

// ---------------------------------------------------------------------------
// One-time prep: W_ih/W_hh -> per-(u,kt) 32x32 bf16 hi/lo MFMA fragment tiles.
// ---------------------------------------------------------------------------
__global__ __launch_bounds__(256) void lstm_prep(
        const float* __restrict__ Wih, const float* __restrict__ Whh,
        const float* __restrict__ bih, const float* __restrict__ bhh,
        unsigned short* __restrict__ wbuf, float* __restrict__ biasbuf) {
    int bid = blockIdx.x;
    int u = bid / KT_TOT, kt = bid % KT_TOT;
    int tid = threadIdx.x;
    int vrow = tid >> 3;
    int kk0  = (tid & 7) * 4;
    int g = vrow >> 3, jj = vrow & 7;
    size_t srow = (size_t)g * H_SZ + u * 8 + jj;
    const float* src = (kt < KT_X)
        ? (Wih + srow * H_SZ + kt * 32 + kk0)
        : (Whh + srow * H_SZ + (kt - KT_X) * 32 + kk0);
    float4 v = *(const float4*)src;
    float f[4] = {v.x, v.y, v.z, v.w};
    unsigned short hi[4], lo[4];
#pragma unroll
    for (int i = 0; i < 4; ++i) {
        hi[i] = f2bf_rne(f[i]);
        lo[i] = f2bf_rne(f[i] - bf2f(hi[i]));
    }
    size_t tbase = ((size_t)u * KT_TOT + kt) * 2048;
    unsigned short* dhi = wbuf + tbase + vrow * 32 + kk0;
    unsigned short* dlo = dhi + 1024;
    *(ushort4*)dhi = make_ushort4(hi[0], hi[1], hi[2], hi[3]);
    *(ushort4*)dlo = make_ushort4(lo[0], lo[1], lo[2], lo[3]);

    if (kt == 0 && tid < 32) {
        int vv = tid;
        size_t r = (size_t)(vv >> 3) * H_SZ + u * 8 + (vv & 7);
        biasbuf[u * 32 + vv] = bih[r] + bhh[r];
    }
}

// ---------------------------------------------------------------------------
// One-time x split: x f32 -> xhi/xlo bf16. 6,553,600 float4s exactly.
// ---------------------------------------------------------------------------
__global__ __launch_bounds__(256) void lstm_xsplit(
        const float* __restrict__ x, unsigned short* __restrict__ xhi,
        unsigned short* __restrict__ xlo) {
    size_t i = (size_t)blockIdx.x * 256 + threadIdx.x;
    float4 v = ((const float4*)x)[i];
    ushort4 h, l;
    split2(v.x, h.x, l.x); split2(v.y, h.y, l.y);
    split2(v.z, h.z, l.z); split2(v.w, h.w, l.w);
    ((ushort4*)xhi)[i] = h;
    ((ushort4*)xlo)[i] = l;
}

// ---------------------------------------------------------------------------
// Phase helpers (nt-merged: one A set feeds both nt output quadrants).
// w0 points at col-0 fragment base; col-1 is +512 shorts, lo blocks +1024.
// ---------------------------------------------------------------------------
#define MFMA __builtin_amdgcn_mfma_f32_16x16x32_bf16

template<int NKT>
__device__ __forceinline__ void xphase_pre_nt(const unsigned short* xh,
                                              const unsigned short* xl,
                                              const unsigned short* w0,
                                              f32x4& a0, f32x4& a1) {
    bf16x8 ah[NKT], al[NKT];
#pragma unroll
    for (int i = 0; i < NKT; ++i) {
        ah[i] = *(const bf16x8*)(xh + i * 32);
        al[i] = *(const bf16x8*)(xl + i * 32);
    }
#pragma unroll
    for (int i = 0; i < NKT; ++i) {
        const unsigned short* wt = w0 + (size_t)i * 2048;
        bf16x8 bh0 = *(const bf16x8*)(wt);
        bf16x8 bl0 = *(const bf16x8*)(wt + 1024);
        bf16x8 bh1 = *(const bf16x8*)(wt + 512);
        bf16x8 bl1 = *(const bf16x8*)(wt + 1536);
        a0 = MFMA(ah[i], bh0, a0, 0, 0, 0);
        a1 = MFMA(ah[i], bh1, a1, 0, 0, 0);
        a0 = MFMA(ah[i], bl0, a0, 0, 0, 0);
        a1 = MFMA(ah[i], bl1, a1, 0, 0, 0);
        a0 = MFMA(al[i], bh0, a0, 0, 0, 0);
        a1 = MFMA(al[i], bh1, a1, 0, 0, 0);
    }
}

template<int NKT>
__device__ __forceinline__ void xphase_cvt_nt(const float* xp,
                                              const unsigned short* w0,
                                              f32x4& a0, f32x4& a1) {
    float4 xr[2 * NKT];
#pragma unroll
    for (int i = 0; i < NKT; ++i) {
        xr[2 * i]     = *(const float4*)(xp + i * 32);
        xr[2 * i + 1] = *(const float4*)(xp + i * 32 + 4);
    }
#pragma unroll
    for (int i = 0; i < NKT; ++i) {
        float f[8] = {xr[2*i].x, xr[2*i].y, xr[2*i].z, xr[2*i].w,
                      xr[2*i+1].x, xr[2*i+1].y, xr[2*i+1].z, xr[2*i+1].w};
        bf16x8 ah, al;
#pragma unroll
        for (int j = 0; j < 8; ++j) {
            unsigned short h16, l16;
            split2(f[j], h16, l16);
            ah[j] = (short)h16; al[j] = (short)l16;
        }
        const unsigned short* wt = w0 + (size_t)i * 2048;
        bf16x8 bh0 = *(const bf16x8*)(wt);
        bf16x8 bl0 = *(const bf16x8*)(wt + 1024);
        bf16x8 bh1 = *(const bf16x8*)(wt + 512);
        bf16x8 bl1 = *(const bf16x8*)(wt + 1536);
        a0 = MFMA(ah, bh0, a0, 0, 0, 0);
        a1 = MFMA(ah, bh1, a1, 0, 0, 0);
        a0 = MFMA(ah, bl0, a0, 0, 0, 0);
        a1 = MFMA(ah, bl1, a1, 0, 0, 0);
        a0 = MFMA(al, bh0, a0, 0, 0, 0);
        a1 = MFMA(al, bh1, a1, 0, 0, 0);
    }
}

template<int NKT>
__device__ __forceinline__ void hphase_nt(const unsigned short* hh,
                                          const unsigned short* hl,
                                          const unsigned short* w0,
                                          f32x4& a0, f32x4& a1) {
    i32x4 ah[NKT], al[NKT];
#pragma unroll
    for (int i = 0; i < NKT; ++i) ah[i] = ld16_sc1(hh + i * 32);
#pragma unroll
    for (int i = 0; i < NKT; ++i) al[i] = ld16_sc1(hl + i * 32);
    asm volatile("s_waitcnt vmcnt(0)" ::: "memory");
    __builtin_amdgcn_sched_barrier(0);      // rule #18: keep MFMAs below wait
#pragma unroll
    for (int i = 0; i < NKT; ++i) {
        const unsigned short* wt = w0 + (size_t)i * 2048;
        bf16x8 bh0 = *(const bf16x8*)(wt);
        bf16x8 bl0 = *(const bf16x8*)(wt + 1024);
        bf16x8 bh1 = *(const bf16x8*)(wt + 512);
        bf16x8 bl1 = *(const bf16x8*)(wt + 1536);
        CvtAB A, L; A.i = ah[i]; L.i = al[i];
        a0 = MFMA(A.b, bh0, a0, 0, 0, 0);
        a1 = MFMA(A.b, bh1, a1, 0, 0, 0);
        a0 = MFMA(A.b, bl0, a0, 0, 0, 0);
        a1 = MFMA(A.b, bl1, a1, 0, 0, 0);
        a0 = MFMA(L.b, bh0, a0, 0, 0, 0);
        a1 = MFMA(L.b, bh1, a1, 0, 0, 0);
    }
}

// ---------------------------------------------------------------------------
// Persistent kernel: 200 blocks (u, mhalf) x 512 threads (8 waves).
// Wave w: mt=w&1 (batch 16-row quadrant), kq=w>>1 (K quarter: 7/6/6/6 kt).
// Each wave computes BOTH nt output quadrants (2 accumulators) from one A set.
// Per step: hphase -> gl exchange -> epilogue -> sync -> arrive(flag) ->
//           xphase(t+1) overlap -> [block0: poll all flags, publish gen |
//           others: poll gen] -> sync.
// ---------------------------------------------------------------------------
__global__ __launch_bounds__(512, 2) void lstm_persist(
        const float* __restrict__ x,
        const unsigned short* __restrict__ wbuf,
        const float* __restrict__ biasbuf,
        unsigned short* __restrict__ hhi,   // [2][64][800]
        unsigned short* __restrict__ hlo,
        float* __restrict__ cbuf,
        float* __restrict__ out,
        unsigned int* __restrict__ flags,   // [NBLK]; gen = flags[208]
        const unsigned short* __restrict__ xhi,
        const unsigned short* __restrict__ xlo,
        int use_pre) {
    extern __shared__ unsigned short whh[];   // 25 kt * 2048 shorts = 102400 B
    __shared__ float gl[4][32][33];           // per-quarter partial sums

    unsigned int* gen = flags + 208;

    int bid = blockIdx.x;
    int u = bid >> 1, mhalf = bid & 1;
    int tid = threadIdx.x;
    int lane = tid & 63;
    int w = tid >> 6;
    int mt = w & 1, kq = w >> 1;
    int rlane = lane & 15, ksel = lane >> 4, kgrp = ksel * 8;
    int brow = mhalf * 32 + mt * 16 + rlane;
    int k0 = (kq == 0) ? 0 : (kq == 1) ? 7 : (kq == 2) ? 13 : 19;

    // ---- stage this u's W_hh tiles (kt 25..49) into LDS ----
    {
        const uint4* src = (const uint4*)(wbuf + ((size_t)u * KT_TOT + KT_X) * 2048);
        uint4* dst = (uint4*)whh;
        for (int g = tid; g < 6400; g += 512) dst[g] = src[g];
    }
    __syncthreads();

    // fragment base pointers (col-0; col-1 at +512, lo at +1024)
    const unsigned short* wih0 =
        wbuf + (size_t)u * KT_TOT * 2048 + (size_t)k0 * 2048 + rlane * 32 + kgrp;
    const unsigned short* whh0 = whh + (size_t)k0 * 2048 + rlane * 32 + kgrp;

    // epilogue constants (tid<128 -> 32 batch-rows x 4 unit-pairs)
    int bl_ = tid >> 2, jp = (tid & 3) * 2;
    int b  = mhalf * 32 + bl_;
    size_t sidx = (size_t)b * H_SZ + u * 8 + jp;
    float bi0 = 0.f, bf0 = 0.f, bg0 = 0.f, bo0 = 0.f;
    float bi1 = 0.f, bf1 = 0.f, bg1 = 0.f, bo1 = 0.f;
    if (tid < 128) {
        bi0 = biasbuf[u * 32 + jp];          bi1 = biasbuf[u * 32 + jp + 1];
        bf0 = biasbuf[u * 32 + 8 + jp];      bf1 = biasbuf[u * 32 + 8 + jp + 1];
        bg0 = biasbuf[u * 32 + 16 + jp];     bg1 = biasbuf[u * 32 + 16 + jp + 1];
        bo0 = biasbuf[u * 32 + 24 + jp];     bo1 = biasbuf[u * 32 + 24 + jp + 1];
    }

    auto do_xphase = [&](int tt, f32x4& a0, f32x4& a1) {
        if (use_pre) {
            const unsigned short* xh =
                xhi + ((size_t)tt * B_SZ + brow) * H_SZ + k0 * 32 + kgrp;
            const unsigned short* xl =
                xlo + ((size_t)tt * B_SZ + brow) * H_SZ + k0 * 32 + kgrp;
            if (kq == 0)      xphase_pre_nt<7>(xh, xl, wih0, a0, a1);
            else if (kq == 1) xphase_pre_nt<6>(xh, xl, wih0, a0, a1);
            else if (kq == 2) xphase_pre_nt<6>(xh, xl, wih0, a0, a1);
            else              xphase_pre_nt<6>(xh, xl, wih0, a0, a1);
        } else {
            const float* xrow =
                x + ((size_t)tt * B_SZ + brow) * H_SZ + k0 * 32 + kgrp;
            if (kq == 0)      xphase_cvt_nt<7>(xrow, wih0, a0, a1);
            else if (kq == 1) xphase_cvt_nt<6>(xrow, wih0, a0, a1);
            else if (kq == 2) xphase_cvt_nt<6>(xrow, wih0, a0, a1);
            else              xphase_cvt_nt<6>(xrow, wih0, a0, a1);
        }
    };

    f32x4 a0 = {0.f, 0.f, 0.f, 0.f}, a1 = {0.f, 0.f, 0.f, 0.f};
    do_xphase(0, a0, a1);

    for (int t = 0; t < T_STEPS; ++t) {
        // ---- h phase: A = h_{t-1} via 16B sc1 loads, B from LDS ----
        {
            int pprev = (t + 1) & 1;
            const unsigned short* hh =
                hhi + (size_t)pprev * 51200 + (size_t)brow * H_SZ + k0 * 32 + kgrp;
            const unsigned short* hl =
                hlo + (size_t)pprev * 51200 + (size_t)brow * H_SZ + k0 * 32 + kgrp;
            if (kq == 0)      hphase_nt<7>(hh, hl, whh0, a0, a1);
            else if (kq == 1) hphase_nt<6>(hh, hl, whh0, a0, a1);
            else if (kq == 2) hphase_nt<6>(hh, hl, whh0, a0, a1);
            else              hphase_nt<6>(hh, hl, whh0, a0, a1);
        }

        // ---- gate exchange (per-quarter partials) ----
#pragma unroll
        for (int j = 0; j < 4; ++j) {
            int row = mt * 16 + ksel * 4 + j;
            gl[kq][row][rlane]      = a0[j];
            gl[kq][row][16 + rlane] = a1[j];
        }
        __syncthreads();

        // ---- epilogue: 128 threads, 2 units each ----
        if (tid < 128) {
            float gi0 = gl[0][bl_][jp]   + gl[1][bl_][jp]   + gl[2][bl_][jp]   + gl[3][bl_][jp]   + bi0;
            float gi1 = gl[0][bl_][jp+1] + gl[1][bl_][jp+1] + gl[2][bl_][jp+1] + gl[3][bl_][jp+1] + bi1;
            float gf0 = gl[0][bl_][8+jp]   + gl[1][bl_][8+jp]   + gl[2][bl_][8+jp]   + gl[3][bl_][8+jp]   + bf0;
            float gf1 = gl[0][bl_][8+jp+1] + gl[1][bl_][8+jp+1] + gl[2][bl_][8+jp+1] + gl[3][bl_][8+jp+1] + bf1;
            float gg0 = gl[0][bl_][16+jp]   + gl[1][bl_][16+jp]   + gl[2][bl_][16+jp]   + gl[3][bl_][16+jp]   + bg0;
            float gg1 = gl[0][bl_][16+jp+1] + gl[1][bl_][16+jp+1] + gl[2][bl_][16+jp+1] + gl[3][bl_][16+jp+1] + bg1;
            float go0 = gl[0][bl_][24+jp]   + gl[1][bl_][24+jp]   + gl[2][bl_][24+jp]   + gl[3][bl_][24+jp]   + bo0;
            float go1 = gl[0][bl_][24+jp+1] + gl[1][bl_][24+jp+1] + gl[2][bl_][24+jp+1] + gl[3][bl_][24+jp+1] + bo1;

            f32x2 cv = *(f32x2*)&cbuf[sidx];
            float cn0 = sigmoid_fast(gf0) * cv[0] + sigmoid_fast(gi0) * tanh_fast(gg0);
            float cn1 = sigmoid_fast(gf1) * cv[1] + sigmoid_fast(gi1) * tanh_fast(gg1);
            float hn0 = sigmoid_fast(go0) * tanh_fast(cn0);
            float hn1 = sigmoid_fast(go1) * tanh_fast(cn1);
            f32x2 cw = {cn0, cn1};
            *(f32x2*)&cbuf[sidx] = cw;
            f32x2 ov = {hn0, hn1};
            __builtin_nontemporal_store(ov,
                (f32x2*)&out[((size_t)t * B_SZ + b) * H_SZ + u * 8 + jp]);
            unsigned short h0h, h0l, h1h, h1l;
            split2(hn0, h0h, h0l);
            split2(hn1, h1h, h1l);
            size_t pcur = (size_t)(t & 1) * 51200;
            __hip_atomic_store((unsigned int*)&hhi[pcur + sidx],
                               (unsigned)h0h | ((unsigned)h1h << 16),
                               __ATOMIC_RELAXED, __HIP_MEMORY_SCOPE_AGENT);
            __hip_atomic_store((unsigned int*)&hlo[pcur + sidx],
                               (unsigned)h0l | ((unsigned)h1l << 16),
                               __ATOMIC_RELAXED, __HIP_MEMORY_SCOPE_AGENT);
        }

        // ---- drain h stores (syncthreads = vmcnt(0) each wave), arrive ----
        __syncthreads();
        if (tid == 0)
            __hip_atomic_store(flags + bid, (unsigned)(t + 1),
                               __ATOMIC_RELAXED, __HIP_MEMORY_SCOPE_AGENT);

        // ---- overlap: next step's x contribution while others arrive ----
        a0 = (f32x4){0.f, 0.f, 0.f, 0.f};
        a1 = (f32x4){0.f, 0.f, 0.f, 0.f};
        if (t + 1 < T_STEPS)
            do_xphase(t + 1, a0, a1);

        // ---- hierarchical barrier ----
        if (bid == 0) {
            if (tid < NBLK) {
                while (__hip_atomic_load(flags + tid, __ATOMIC_RELAXED,
                                         __HIP_MEMORY_SCOPE_AGENT) < (unsigned)(t + 1))
                    __builtin_amdgcn_s_sleep(1);
            }
            __syncthreads();
            if (tid == 0)
                __hip_atomic_store(gen, (unsigned)(t + 1),
                                   __ATOMIC_RELAXED, __HIP_MEMORY_SCOPE_AGENT);
        } else {
            if (tid == 0) {
                while (__hip_atomic_load(gen, __ATOMIC_RELAXED,
                                         __HIP_MEMORY_SCOPE_AGENT) < (unsigned)(t + 1))
                    __builtin_amdgcn_s_sleep(1);
            }
            __syncthreads();
        }
        // all blocks' h_t visible at coherence point (flag stored after each
        // producer's vmcnt drain; gen stored after block0 observed all flags).
    }
}

// ---------------------------------------------------------------------------
extern "C" void kernel_launch(void* const* d_in, const int* in_sizes, int n_in,
                              void* d_out, int out_size, void* d_ws, size_t ws_size,
                              hipStream_t stream) {
    const float* x   = (const float*)d_in[0];
    const float* Wih = (const float*)d_in[1];
    const float* Whh = (const float*)d_in[2];
    const float* bih = (const float*)d_in[3];
    const float* bhh = (const float*)d_in[4];
    float* out = (float*)d_out;

    char* ws = (char*)d_ws;
    float* cbuf          = (float*)(ws + OFF_C);
    unsigned short* hhi  = (unsigned short*)(ws + OFF_HHI);
    unsigned short* hlo  = (unsigned short*)(ws + OFF_HLO);
    unsigned int* flags  = (unsigned int*)(ws + OFF_FLAGS);
    float* biasbuf       = (float*)(ws + OFF_BIAS);
    unsigned short* wbuf = (unsigned short*)(ws + OFF_WBUF);
    unsigned short* xhi  = (unsigned short*)(ws + OFF_XHI);
    unsigned short* xlo  = (unsigned short*)(ws + OFF_XLO);
    int use_pre = (ws_size >= WS_NEED_PRE) ? 1 : 0;

    // zero c, h[2] (hi/lo), flags+gen (ws is re-poisoned before each call)
    hipMemsetAsync(ws, 0, OFF_BIAS, stream);

    lstm_prep<<<NU * KT_TOT, 256, 0, stream>>>(Wih, Whh, bih, bhh, wbuf, biasbuf);
    if (use_pre)
        lstm_xsplit<<<25600, 256, 0, stream>>>(x, xhi, xlo);

    hipFuncSetAttribute((const void*)lstm_persist,
                        hipFuncAttributeMaxDynamicSharedMemorySize, 102400);
    void* args[] = {(void*)&x, (void*)&wbuf, (void*)&biasbuf, (void*)&hhi,
                    (void*)&hlo, (void*)&cbuf, (void*)&out, (void*)&flags,
                    (void*)&xhi, (void*)&xlo, (void*)&use_pre};
    hipLaunchCooperativeKernel((const void*)lstm_persist, dim3(NBLK), dim3(512),
                               args, 102400, stream);
}